// Round 5
// baseline (940.825 us; speedup 1.0000x reference)
//
#include <hip/hip_runtime.h>

#define BATCH 32
#define SEQT 1000
#define INSZ 4
#define HID 2048
#define NOISE_STD 0.05f
#define ALPHA 0.2f
#define ONE_M_ALPHA (1.0f - ALPHA)

#define NTHREADS 512
#define NWAVES 8           // 2 waves per SIMD (R3: 1/SIMD regressed)
#define EPT 4              // HID / NTHREADS
#define PF 4               // prefetch depth (== unroll)

typedef float v2f __attribute__((ext_vector_type(2)));

__device__ __forceinline__ v2f vfma(v2f a, v2f b, v2f c) { return a * b + c; } // v_pk_fma_f32

// ---- DPP wave reduction (VALU pipe) ----
template<int CTRL>
__device__ __forceinline__ float dpp_add(float x) {
    int s = __builtin_amdgcn_update_dpp(0, __float_as_int(x), CTRL, 0xF, 0xF, true);
    return x + __int_as_float(s);
}

__device__ __forceinline__ float wave_sum64_to_lane63(float x) {
    x = dpp_add<0x111>(x);   // row_shr:1
    x = dpp_add<0x112>(x);   // row_shr:2
    x = dpp_add<0x114>(x);   // row_shr:4
    x = dpp_add<0x118>(x);   // row_shr:8
    x = dpp_add<0x142>(x);   // row_bcast:15
    x = dpp_add<0x143>(x);   // row_bcast:31 -> lane63 = total
    return x;
}

__device__ __forceinline__ float sum8_to_lane7(float x) {
    x = dpp_add<0x111>(x);
    x = dpp_add<0x112>(x);
    x = dpp_add<0x114>(x);   // lane7 = sum of lanes 0..7
    return x;
}

__device__ __forceinline__ float read_lane7(float x) {
    return __int_as_float(__builtin_amdgcn_readlane(__float_as_int(x), 7));
}

__device__ __forceinline__ float fast_tanh(float x) {
    float e = __expf(2.0f * x);
    return 1.0f - 2.0f * __builtin_amdgcn_rcpf(e + 1.0f);
}

// LDS-only barrier: does NOT drain vmcnt (global noise prefetch stays in flight)
#define LDS_BARRIER() __asm__ volatile("s_waitcnt lgkmcnt(0)\ns_barrier" ::: "memory")

__global__ __launch_bounds__(NTHREADS)
void rnn_kernel(const float* __restrict__ input,
                const float* __restrict__ noise,
                const float* __restrict__ wi_w,
                const float* __restrict__ m_w,
                const float* __restrict__ n_w,
                const float* __restrict__ wo_w,
                const float* __restrict__ wi_b,
                const float* __restrict__ m_b,
                const float* __restrict__ n_b,
                const float* __restrict__ h0_w,
                const float* __restrict__ gb,
                const float* __restrict__ sup,
                float* __restrict__ out)
{
    // ONLY LDS: 2 (parity) x 8 waves x float4 = 256 B. No sIn staging.
    __shared__ __align__(16) float4 sRed[2][NWAVES]; // (y0p, y1p, oz_prev, ow_prev)

    const int b    = blockIdx.x;
    const int tid  = threadIdx.x;
    const int wave = tid >> 6;
    const int lane = tid & 63;

    // ---- one-time proxy params; ownership h = tid*4 + e (contiguous -> coalesced noise)
    v2f wiA[INSZ][2];                // alpha * wi, packed pairs
    v2f mA0v[2], mA1v[2], n0v[2], n1v[2], wo0v[2], wo1v[2], hv[2];
    v2f q0 = {0.f, 0.f}, q1 = q0, q2 = q0, q3 = q0;  // pair partial accumulators

    #pragma unroll
    for (int e = 0; e < EPT; ++e) {
        const int h = tid * 4 + e;
        const int pi = e >> 1, pc = e & 1;
        float gv[8];
        #pragma unroll
        for (int g = 0; g < 8; ++g) gv[g] = gb[g * HID + h];
        const float s0 = sup[h];
        const float s1 = sup[HID + h];

        auto mix = [&](const float* w) -> float {
            float a0 = 0.f, a1 = 0.f;
            #pragma unroll
            for (int g = 0; g < 8; ++g) { a0 += w[g] * gv[g]; a1 += w[8 + g] * gv[g]; }
            return s0 * a0 + s1 * a1;
        };

        #pragma unroll
        for (int i = 0; i < INSZ; ++i)
            wiA[i][pi][pc] = ALPHA * (mix(wi_w + i * 16) + wi_b[i * 2 + 0] * s0 + wi_b[i * 2 + 1] * s1);
        mA0v[pi][pc] = ALPHA * (mix(m_w)      + m_b[0] * s0 + m_b[1] * s1);
        mA1v[pi][pc] = ALPHA * (mix(m_w + 16) + m_b[2] * s0 + m_b[3] * s1);
        const float n0 = mix(n_w)      + n_b[0] * s0 + n_b[1] * s1;
        const float n1 = mix(n_w + 16) + n_b[2] * s0 + n_b[3] * s1;
        const float w0 = mix(wo_w);
        const float w1 = mix(wo_w + 16);
        n0v[pi][pc] = n0;  n1v[pi][pc] = n1;
        wo0v[pi][pc] = w0; wo1v[pi][pc] = w1;
        {
            float a0 = 0.f, a1 = 0.f;
            #pragma unroll
            for (int g = 0; g < 8; ++g) { a0 += h0_w[g] * gv[g]; a1 += h0_w[8 + g] * gv[g]; }
            const float h0v = s0 * a0 + s1 * a1;
            hv[pi][pc] = h0v;
            const float r = fast_tanh(h0v);
            q0[pc] += r * n0;  q1[pc] += r * n1;
            q2[pc] += r * w0;  q3[pc] += r * w1;
        }
    }

    // noise: one coalesced float4 per lane per step; PF-deep register prefetch
    const float4* nP4 = reinterpret_cast<const float4*>(noise + (size_t)b * SEQT * HID);
    const int rowStride = HID / 4;
    float4 nb0 = nP4[0 * rowStride + tid];
    float4 nb1 = nP4[1 * rowStride + tid];
    float4 nb2 = nP4[2 * rowStride + tid];
    float4 nb3 = nP4[3 * rowStride + tid];

    // input: block-uniform rows straight from global (scalarizes to s_load), PF-deep
    const float4* inRow4 = reinterpret_cast<const float4*>(input + (size_t)b * SEQT * INSZ);
    float4 inv0 = inRow4[0];
    float4 inv1 = inRow4[1];
    float4 inv2 = inRow4[2];
    float4 inv3 = inRow4[3];

    float* outRow = out + (size_t)b * SEQT * 2;

    // o-wave-sums of r^{(t-1)}, computed post-barrier each step, written next step.
    float oz = 0.f, ow = 0.f;

    auto do_step = [&](int t, float4& nbuf, float4& invReg) {
        const int par = t & 1;
        // ---- pre-barrier (short): y-trees only + single b128 write
        const float p0 = q0.x + q0.y, p1 = q1.x + q1.y;
        const float w0 = wave_sum64_to_lane63(p0);
        const float w1 = wave_sum64_to_lane63(p1);
        if (lane == 63) sRed[par][wave] = make_float4(w0, w1, oz, ow);

        LDS_BARRIER();                    // lgkm-only; vmcnt prefetches stay in flight

        // ---- post-barrier: issue the LDS read first, then fill its latency
        const float4 pr = sRed[par][lane & 7];   // broadcast b128, conflict-free

        // filler 1: o-trees for r^{(t)} (current q2,q3, before phase C overwrites)
        const float p2 = q2.x + q2.y, p3 = q3.x + q3.y;
        const float ozn = wave_sum64_to_lane63(p2);
        const float own = wave_sum64_to_lane63(p3);

        // filler 2: prefetch issues
        const int tpre = (t + PF < SEQT) ? (t + PF) : (SEQT - 1);
        const float4 nv4 = nbuf;
        nbuf = nP4[(size_t)tpre * rowStride + tid];   // global prefetch (vmcnt)
        const float4 inv = invReg;
        invReg = inRow4[tpre];                        // uniform prefetch (smem/lgkm)

        // filler 3: phase A (independent of y), packed fma
        const v2f nlo = {nv4.x, nv4.y}, nhi = {nv4.z, nv4.w};
        v2f acc0 = wiA[0][0] * inv.x;
        v2f acc1 = wiA[0][1] * inv.x;
        acc0 = vfma(wiA[1][0], inv.y, acc0);  acc1 = vfma(wiA[1][1], inv.y, acc1);
        acc0 = vfma(wiA[2][0], inv.z, acc0);  acc1 = vfma(wiA[2][1], inv.z, acc1);
        acc0 = vfma(wiA[3][0], inv.w, acc0);  acc1 = vfma(wiA[3][1], inv.w, acc1);
        acc0 = acc0 + nlo * NOISE_STD;        acc1 = acc1 + nhi * NOISE_STD;
        acc0 = vfma(hv[0], ONE_M_ALPHA, acc0); acc1 = vfma(hv[1], ONE_M_ALPHA, acc1);

        // y: 3-level DPP over 8 wave-partials + uniform broadcast
        const float y0 = read_lane7(sum8_to_lane7(pr.x));
        const float y1 = read_lane7(sum8_to_lane7(pr.y));

        // output row t-2 (= wo . r^{(t-1)}): rotated designated wave, direct store
        if (t >= 2 && wave == (t & 7)) {
            const float o0 = sum8_to_lane7(pr.z);
            const float o1 = sum8_to_lane7(pr.w);
            if (lane == 7)
                *reinterpret_cast<float2*>(outRow + (t - 2) * 2) = make_float2(o0, o1);
        }
        oz = ozn; ow = own;

        // ---- phase C: finish update + next partials (packed)
        v2f h2a = vfma(mA1v[0], y1, acc0);
        v2f h2b = vfma(mA1v[1], y1, acc1);
        h2a = vfma(mA0v[0], y0, h2a);
        h2b = vfma(mA0v[1], y0, h2b);
        hv[0] = h2a; hv[1] = h2b;
        v2f r2a, r2b;
        r2a.x = fast_tanh(h2a.x); r2a.y = fast_tanh(h2a.y);
        r2b.x = fast_tanh(h2b.x); r2b.y = fast_tanh(h2b.y);
        q0 = r2a * n0v[0];  q0 = vfma(r2b, n0v[1], q0);
        q1 = r2a * n1v[0];  q1 = vfma(r2b, n1v[1], q1);
        q2 = r2a * wo0v[0]; q2 = vfma(r2b, wo0v[1], q2);
        q3 = r2a * wo1v[0]; q3 = vfma(r2b, wo1v[1], q3);
    };

    for (int t = 0; t < SEQT; t += PF) {
        do_step(t,     nb0, inv0);
        do_step(t + 1, nb1, inv1);
        do_step(t + 2, nb2, inv2);
        do_step(t + 3, nb3, inv3);
    }

    // epilogue: rows 998 (wo.r^{(999)} = oz/ow) and 999 (wo.r^{(1000)} = final q2,q3)
    {
        const float p2 = q2.x + q2.y, p3 = q3.x + q3.y;
        const float w2 = wave_sum64_to_lane63(p2);
        const float w3 = wave_sum64_to_lane63(p3);
        if (lane == 63) sRed[0][wave] = make_float4(w2, w3, oz, ow);
        LDS_BARRIER();
        if (wave == 0) {
            const float4 pr = sRed[0][lane & 7];
            const float a999 = sum8_to_lane7(pr.x);
            const float b999 = sum8_to_lane7(pr.y);
            const float a998 = sum8_to_lane7(pr.z);
            const float b998 = sum8_to_lane7(pr.w);
            if (lane == 7) {
                *reinterpret_cast<float2*>(outRow + 998 * 2) = make_float2(a998, b998);
                *reinterpret_cast<float2*>(outRow + 999 * 2) = make_float2(a999, b999);
            }
        }
    }
}

extern "C" void kernel_launch(void* const* d_in, const int* in_sizes, int n_in,
                              void* d_out, int out_size, void* d_ws, size_t ws_size,
                              hipStream_t stream) {
    const float* input = (const float*)d_in[0];
    const float* noise = (const float*)d_in[1];
    const float* wi_w  = (const float*)d_in[2];
    const float* m_w   = (const float*)d_in[3];
    const float* n_w   = (const float*)d_in[4];
    const float* wo_w  = (const float*)d_in[5];
    const float* wi_b  = (const float*)d_in[6];
    const float* m_b   = (const float*)d_in[7];
    const float* n_b   = (const float*)d_in[8];
    const float* h0_w  = (const float*)d_in[9];
    const float* gb    = (const float*)d_in[10];
    const float* sup   = (const float*)d_in[11];
    float* out = (float*)d_out;

    rnn_kernel<<<dim3(BATCH), dim3(NTHREADS), 0, stream>>>(
        input, noise, wi_w, m_w, n_w, wo_w, wi_b, m_b, n_b, h0_w, gb, sup, out);
}

// Round 6
// 874.614 us; speedup vs baseline: 1.0757x; 1.0757x over previous
//
#include <hip/hip_runtime.h>

#define BATCH 32
#define SEQT 1000
#define INSZ 4
#define HID 2048
#define NOISE_STD 0.05f
#define ALPHA 0.2f
#define ONE_M_ALPHA (1.0f - ALPHA)

#define NTHREADS 512
#define NWAVES 8           // 2 waves per SIMD (R3: 1/SIMD regressed)
#define EPT 4              // HID / NTHREADS
#define PF 4               // prefetch depth (== unroll)

typedef float v2f __attribute__((ext_vector_type(2)));

__device__ __forceinline__ v2f vfma(v2f a, v2f b, v2f c) { return a * b + c; } // v_pk_fma_f32

// ---- DPP wave reduction (VALU pipe) ----
template<int CTRL>
__device__ __forceinline__ float dpp_add(float x) {
    int s = __builtin_amdgcn_update_dpp(0, __float_as_int(x), CTRL, 0xF, 0xF, true);
    return x + __int_as_float(s);
}

__device__ __forceinline__ float wave_sum64_to_lane63(float x) {
    x = dpp_add<0x111>(x);   // row_shr:1
    x = dpp_add<0x112>(x);   // row_shr:2
    x = dpp_add<0x114>(x);   // row_shr:4
    x = dpp_add<0x118>(x);   // row_shr:8
    x = dpp_add<0x142>(x);   // row_bcast:15
    x = dpp_add<0x143>(x);   // row_bcast:31 -> lane63 = total
    return x;
}

__device__ __forceinline__ float sum8_to_lane7(float x) {
    x = dpp_add<0x111>(x);
    x = dpp_add<0x112>(x);
    x = dpp_add<0x114>(x);   // lane7 = sum of lanes 0..7
    return x;
}

__device__ __forceinline__ float read_lane7(float x) {
    return __int_as_float(__builtin_amdgcn_readlane(__float_as_int(x), 7));
}

// tanh via Pade[5/4] (continued-fraction truncation) + clamp.
// tanh(x) ~= x(945+105x^2+x^4)/(945+420x^2+15x^4); exact to O(x^9),
// max err <= ~7e-4 with clamp to [-1,1] (ratio >= tanh for |x|>~3.8).
// No v_exp (quarter-rate) on the phase-C critical chain; all pk except 2 rcp.
__device__ __forceinline__ v2f pade_tanh(v2f x) {
    const v2f x2 = x * x;
    const v2f a  = x2 + 105.0f;
    const v2f num = x * vfma(x2, a, v2f{945.0f, 945.0f});
    const v2f c  = vfma(x2, v2f{15.0f, 15.0f}, v2f{420.0f, 420.0f});
    const v2f d  = vfma(x2, c, v2f{945.0f, 945.0f});
    v2f r;
    r.x = num.x * __builtin_amdgcn_rcpf(d.x);
    r.y = num.y * __builtin_amdgcn_rcpf(d.y);
    r.x = fminf(fmaxf(r.x, -1.0f), 1.0f);   // v_med3-able
    r.y = fminf(fmaxf(r.y, -1.0f), 1.0f);
    return r;
}

// scalar version for init path
__device__ __forceinline__ float pade_tanh_s(float x) {
    const float x2 = x * x;
    const float num = x * fmaf(x2, x2 + 105.0f, 945.0f);
    const float den = fmaf(x2, fmaf(x2, 15.0f, 420.0f), 945.0f);
    float r = num * __builtin_amdgcn_rcpf(den);
    return fminf(fmaxf(r, -1.0f), 1.0f);
}

// LDS-only barrier: does NOT drain vmcnt (global noise prefetch stays in flight)
#define LDS_BARRIER() __asm__ volatile("s_waitcnt lgkmcnt(0)\ns_barrier" ::: "memory")

__global__ __launch_bounds__(NTHREADS)
void rnn_kernel(const float* __restrict__ input,
                const float* __restrict__ noise,
                const float* __restrict__ wi_w,
                const float* __restrict__ m_w,
                const float* __restrict__ n_w,
                const float* __restrict__ wo_w,
                const float* __restrict__ wi_b,
                const float* __restrict__ m_b,
                const float* __restrict__ n_b,
                const float* __restrict__ h0_w,
                const float* __restrict__ gb,
                const float* __restrict__ sup,
                float* __restrict__ out)
{
    __shared__ float4 sIn4[SEQT];                    // 16000 B input rows (R4: LDS, not global)
    __shared__ __align__(16) float4 sRed[2][NWAVES]; // (y0p, y1p, oz_prev, ow_prev), parity dbuf

    const int b    = blockIdx.x;
    const int tid  = threadIdx.x;
    const int wave = tid >> 6;
    const int lane = tid & 63;

    // stage input rows into LDS (coalesced b128)
    const float4* inRow4 = reinterpret_cast<const float4*>(input + (size_t)b * SEQT * INSZ);
    for (int i = tid; i < SEQT; i += NTHREADS)
        sIn4[i] = inRow4[i];

    // ---- one-time proxy params; ownership h = tid*4 + e (contiguous -> coalesced noise)
    v2f wiA[INSZ][2];                // alpha * wi, packed pairs
    v2f mA0v[2], mA1v[2], n0v[2], n1v[2], wo0v[2], wo1v[2], hv[2];
    v2f q0 = {0.f, 0.f}, q1 = q0, q2 = q0, q3 = q0;  // pair partial accumulators

    #pragma unroll
    for (int e = 0; e < EPT; ++e) {
        const int h = tid * 4 + e;
        const int pi = e >> 1, pc = e & 1;
        float gv[8];
        #pragma unroll
        for (int g = 0; g < 8; ++g) gv[g] = gb[g * HID + h];
        const float s0 = sup[h];
        const float s1 = sup[HID + h];

        auto mix = [&](const float* w) -> float {
            float a0 = 0.f, a1 = 0.f;
            #pragma unroll
            for (int g = 0; g < 8; ++g) { a0 += w[g] * gv[g]; a1 += w[8 + g] * gv[g]; }
            return s0 * a0 + s1 * a1;
        };

        #pragma unroll
        for (int i = 0; i < INSZ; ++i)
            wiA[i][pi][pc] = ALPHA * (mix(wi_w + i * 16) + wi_b[i * 2 + 0] * s0 + wi_b[i * 2 + 1] * s1);
        mA0v[pi][pc] = ALPHA * (mix(m_w)      + m_b[0] * s0 + m_b[1] * s1);
        mA1v[pi][pc] = ALPHA * (mix(m_w + 16) + m_b[2] * s0 + m_b[3] * s1);
        const float n0 = mix(n_w)      + n_b[0] * s0 + n_b[1] * s1;
        const float n1 = mix(n_w + 16) + n_b[2] * s0 + n_b[3] * s1;
        const float w0 = mix(wo_w);
        const float w1 = mix(wo_w + 16);
        n0v[pi][pc] = n0;  n1v[pi][pc] = n1;
        wo0v[pi][pc] = w0; wo1v[pi][pc] = w1;
        {
            float a0 = 0.f, a1 = 0.f;
            #pragma unroll
            for (int g = 0; g < 8; ++g) { a0 += h0_w[g] * gv[g]; a1 += h0_w[8 + g] * gv[g]; }
            const float h0v = s0 * a0 + s1 * a1;
            hv[pi][pc] = h0v;
            const float r = pade_tanh_s(h0v);
            q0[pc] += r * n0;  q1[pc] += r * n1;
            q2[pc] += r * w0;  q3[pc] += r * w1;
        }
    }

    // noise: one coalesced float4 per lane per step; PF-deep register prefetch
    const float4* nP4 = reinterpret_cast<const float4*>(noise + (size_t)b * SEQT * HID);
    const int rowStride = HID / 4;
    float4 nb0 = nP4[0 * rowStride + tid];
    float4 nb1 = nP4[1 * rowStride + tid];
    float4 nb2 = nP4[2 * rowStride + tid];
    float4 nb3 = nP4[3 * rowStride + tid];

    float* outRow = out + (size_t)b * SEQT * 2;

    __syncthreads();                      // sIn4 ready (one full barrier)
    float4 inv0 = sIn4[0];
    float4 inv1 = sIn4[1];
    float4 inv2 = sIn4[2];
    float4 inv3 = sIn4[3];

    // o-wave-sums of r^{(t-1)}, computed post-barrier each step, written next step.
    float oz = 0.f, ow = 0.f;

    auto do_step = [&](int t, float4& nbuf, float4& invReg) {
        const int par = t & 1;
        // ---- pre-barrier (SHORT): y-trees only + single b128 write (o from prev regs)
        const float p0 = q0.x + q0.y, p1 = q1.x + q1.y;
        const float w0 = wave_sum64_to_lane63(p0);
        const float w1 = wave_sum64_to_lane63(p1);
        if (lane == 63) sRed[par][wave] = make_float4(w0, w1, oz, ow);

        LDS_BARRIER();                    // lgkm-only; vmcnt prefetches stay in flight

        // ---- post-barrier: issue the LDS read first, then fill its latency
        const float4 pr = sRed[par][lane & 7];   // broadcast b128, conflict-free

        // filler 1: o-trees for r^{(t)} (current q2,q3 before phase C overwrites)
        const float p2 = q2.x + q2.y, p3 = q3.x + q3.y;
        const float ozn = wave_sum64_to_lane63(p2);
        const float own = wave_sum64_to_lane63(p3);

        // filler 2: prefetch issues (invReg ds_read drains at NEXT step's barrier — hidden)
        const int tpre = (t + PF < SEQT) ? (t + PF) : (SEQT - 1);
        const float4 nv4 = nbuf;
        nbuf = nP4[(size_t)tpre * rowStride + tid];   // global prefetch (vmcnt)
        const float4 inv = invReg;
        invReg = sIn4[tpre];                          // LDS prefetch (lgkm)

        // filler 3: phase A (independent of y), packed fma
        const v2f nlo = {nv4.x, nv4.y}, nhi = {nv4.z, nv4.w};
        v2f acc0 = wiA[0][0] * inv.x;
        v2f acc1 = wiA[0][1] * inv.x;
        acc0 = vfma(wiA[1][0], inv.y, acc0);  acc1 = vfma(wiA[1][1], inv.y, acc1);
        acc0 = vfma(wiA[2][0], inv.z, acc0);  acc1 = vfma(wiA[2][1], inv.z, acc1);
        acc0 = vfma(wiA[3][0], inv.w, acc0);  acc1 = vfma(wiA[3][1], inv.w, acc1);
        acc0 = acc0 + nlo * NOISE_STD;        acc1 = acc1 + nhi * NOISE_STD;
        acc0 = vfma(hv[0], ONE_M_ALPHA, acc0); acc1 = vfma(hv[1], ONE_M_ALPHA, acc1);

        // y: 3-level DPP over 8 wave-partials + uniform broadcast
        const float y0 = read_lane7(sum8_to_lane7(pr.x));
        const float y1 = read_lane7(sum8_to_lane7(pr.y));

        // output row t-2 (= wo . r^{(t-1)}): designated wave only does the o-sum8
        if (t >= 2 && wave == (t & 7)) {
            const float o0 = sum8_to_lane7(pr.z);
            const float o1 = sum8_to_lane7(pr.w);
            if (lane == 7)
                *reinterpret_cast<float2*>(outRow + (t - 2) * 2) = make_float2(o0, o1);
        }
        oz = ozn; ow = own;

        // ---- phase C: finish update + next partials (packed, no exp on the chain)
        v2f h2a = vfma(mA1v[0], y1, acc0);
        v2f h2b = vfma(mA1v[1], y1, acc1);
        h2a = vfma(mA0v[0], y0, h2a);
        h2b = vfma(mA0v[1], y0, h2b);
        hv[0] = h2a; hv[1] = h2b;
        const v2f r2a = pade_tanh(h2a);
        const v2f r2b = pade_tanh(h2b);
        q0 = r2a * n0v[0];  q0 = vfma(r2b, n0v[1], q0);
        q1 = r2a * n1v[0];  q1 = vfma(r2b, n1v[1], q1);
        q2 = r2a * wo0v[0]; q2 = vfma(r2b, wo0v[1], q2);
        q3 = r2a * wo1v[0]; q3 = vfma(r2b, wo1v[1], q3);
    };

    for (int t = 0; t < SEQT; t += PF) {
        do_step(t,     nb0, inv0);
        do_step(t + 1, nb1, inv1);
        do_step(t + 2, nb2, inv2);
        do_step(t + 3, nb3, inv3);
    }

    // epilogue: rows 998 (wo.r^{(999)} = oz/ow) and 999 (wo.r^{(1000)} = final q2,q3)
    {
        const float p2 = q2.x + q2.y, p3 = q3.x + q3.y;
        const float w2 = wave_sum64_to_lane63(p2);
        const float w3 = wave_sum64_to_lane63(p3);
        if (lane == 63) sRed[0][wave] = make_float4(w2, w3, oz, ow);
        LDS_BARRIER();
        if (wave == 0) {
            const float4 pr = sRed[0][lane & 7];
            const float a999 = sum8_to_lane7(pr.x);
            const float b999 = sum8_to_lane7(pr.y);
            const float a998 = sum8_to_lane7(pr.z);
            const float b998 = sum8_to_lane7(pr.w);
            if (lane == 7) {
                *reinterpret_cast<float2*>(outRow + 998 * 2) = make_float2(a998, b998);
                *reinterpret_cast<float2*>(outRow + 999 * 2) = make_float2(a999, b999);
            }
        }
    }
}

extern "C" void kernel_launch(void* const* d_in, const int* in_sizes, int n_in,
                              void* d_out, int out_size, void* d_ws, size_t ws_size,
                              hipStream_t stream) {
    const float* input = (const float*)d_in[0];
    const float* noise = (const float*)d_in[1];
    const float* wi_w  = (const float*)d_in[2];
    const float* m_w   = (const float*)d_in[3];
    const float* n_w   = (const float*)d_in[4];
    const float* wo_w  = (const float*)d_in[5];
    const float* wi_b  = (const float*)d_in[6];
    const float* m_b   = (const float*)d_in[7];
    const float* n_b   = (const float*)d_in[8];
    const float* h0_w  = (const float*)d_in[9];
    const float* gb    = (const float*)d_in[10];
    const float* sup   = (const float*)d_in[11];
    float* out = (float*)d_out;

    rnn_kernel<<<dim3(BATCH), dim3(NTHREADS), 0, stream>>>(
        input, noise, wi_w, m_w, n_w, wo_w, wi_b, m_b, n_b, h0_w, gb, sup, out);
}